// Round 11
// baseline (248.082 us; speedup 1.0000x reference)
//
#include <hip/hip_runtime.h>

#define VOCAB 50257
#define EMBD  300
#define EMBP  320      // EMB padded to multiple of 32 for MFMA K
#define HID   1024
#define B3H   3072
#define BATCH 128
#define NBK3  3142     // ceil(50257/16) : k3 grid, 16 vocab rows/block
#define NKT   32       // K tiles of 32

typedef __attribute__((ext_vector_type(8))) short short8;
typedef __attribute__((ext_vector_type(4))) float f32x4;
typedef unsigned short ushort_t;

__device__ __forceinline__ unsigned short f2bf(float f) {
  unsigned int u = __float_as_uint(f);
  u += 0x7fffu + ((u >> 16) & 1u);
  return (unsigned short)(u >> 16);
}

__device__ __forceinline__ void gload16(const void* g, void* l) {
  __builtin_amdgcn_global_load_lds(
      (const __attribute__((address_space(1))) void*)g,
      (__attribute__((address_space(3))) void*)l, 16, 0, 0);
}

#define MEMF() asm volatile("" ::: "memory")

// ---------------- K0: gather + bf16 casts (x, h, w_ih, w_hh) ----------------
__global__ __launch_bounds__(256) void k0_prep(
    const int* __restrict__ ids, const float* __restrict__ emb,
    const float* __restrict__ hprev, const float* __restrict__ wih,
    const float* __restrict__ whh,
    ushort_t* __restrict__ xbf, ushort_t* __restrict__ hbf,
    ushort_t* __restrict__ wihbf, ushort_t* __restrict__ whhbf) {
  const int NX  = BATCH * EMBP;        // 40960
  const int NH  = BATCH * HID;         // 131072
  const int NWI = B3H * EMBP;          // 983040
  int i = blockIdx.x * 256 + threadIdx.x;
  if (i < NX) {
    int b = i / EMBP, k = i - b * EMBP;
    float f = (k < EMBD) ? emb[(size_t)ids[b] * EMBD + k] : 0.f;
    xbf[i] = f2bf(f);
  } else if (i < NX + NH) {
    int j = i - NX;
    hbf[j] = f2bf(hprev[j]);
  } else if (i < NX + NH + NWI) {
    int j = i - NX - NH;
    int n = j / EMBP, k = j - n * EMBP;
    wihbf[j] = f2bf((k < EMBD) ? wih[(size_t)n * EMBD + k] : 0.f);
  } else {
    int j = (i - NX - NH - NWI) * 8;
    f32x4 a = *(const f32x4*)(whh + j);
    f32x4 b = *(const f32x4*)(whh + j + 4);
    short8 o;
    o[0] = (short)f2bf(a[0]); o[1] = (short)f2bf(a[1]);
    o[2] = (short)f2bf(a[2]); o[3] = (short)f2bf(a[3]);
    o[4] = (short)f2bf(b[0]); o[5] = (short)f2bf(b[1]);
    o[6] = (short)f2bf(b[2]); o[7] = (short)f2bf(b[3]);
    *(short8*)(whhbf + j) = o;
  }
}

// ---------------- K1: gates GEMMs, 1 wave per block, 16 cols, bf16 B ----------------
__global__ __launch_bounds__(64) void k1_gemm_gates(
    const ushort_t* __restrict__ xbf, const ushort_t* __restrict__ hbf,
    const ushort_t* __restrict__ wihbf, const ushort_t* __restrict__ whhbf,
    float* __restrict__ gi, float* __restrict__ gh) {
  const bool is_h = (blockIdx.y == 1);
  const ushort_t* A = is_h ? hbf : xbf;
  const ushort_t* B = is_h ? whhbf : wihbf;
  const int K = is_h ? HID : EMBP;
  const int lane = threadIdx.x;
  const int r = lane & 15, g = lane >> 4;
  const int n = blockIdx.x * 16 + r;
  const ushort_t* brow = B + (size_t)n * K;

  f32x4 acc[8];
#pragma unroll
  for (int i = 0; i < 8; i++) acc[i] = (f32x4){0.f, 0.f, 0.f, 0.f};

#pragma unroll 2
  for (int k0 = 0; k0 < K; k0 += 32) {
    short8 bfr = *(const short8*)(brow + k0 + g * 8);
#pragma unroll
    for (int mi = 0; mi < 8; mi++) {
      short8 afr = *(const short8*)(A + (size_t)(mi * 16 + r) * K + k0 + g * 8);
      acc[mi] = __builtin_amdgcn_mfma_f32_16x16x32_bf16(afr, bfr, acc[mi], 0, 0, 0);
    }
  }
  float* C = is_h ? gh : gi;
#pragma unroll
  for (int mi = 0; mi < 8; mi++)
#pragma unroll
    for (int rr = 0; rr < 4; rr++)
      C[(size_t)(mi * 16 + g * 4 + rr) * B3H + n] = acc[mi][rr];
}

// ---------------- K2: GRU gates -> h_new (f32) + chunk-major bf16 hnbf2 ----------
// hnbf2 layout: ushort idx = kchunk*1024 + row*8 + (k&7), kchunk = k>>3.
// K-tile kt (32 k) of all 128 rows = bytes [kt*8192, kt*8192+8192) CONTIGUOUS.
__global__ __launch_bounds__(256) void k2_gates(
    const float* __restrict__ gi, const float* __restrict__ gh,
    const float* __restrict__ bih, const float* __restrict__ bhh,
    const float* __restrict__ hprev,
    float* __restrict__ hnew_out, ushort_t* __restrict__ hnbf2) {
  int t = blockIdx.x * 256 + threadIdx.x;   // 0..16383
  int row = t >> 7, kc = t & 127;
  int k0 = kc * 8;
  size_t gb = (size_t)row * B3H;
  float hv[8];
  short8 o;
#pragma unroll
  for (int e = 0; e < 8; ++e) {
    int j = k0 + e;
    float ir  = gi[gb + j]           + bih[j];
    float iz  = gi[gb + HID + j]     + bih[HID + j];
    float in_ = gi[gb + 2*HID + j]   + bih[2*HID + j];
    float hr  = gh[gb + j]           + bhh[j];
    float hz  = gh[gb + HID + j]     + bhh[HID + j];
    float hn  = gh[gb + 2*HID + j]   + bhh[2*HID + j];
    float rg = 1.f / (1.f + expf(-(ir + hr)));
    float zg = 1.f / (1.f + expf(-(iz + hz)));
    float ng = tanhf(in_ + rg * hn);
    float h  = hprev[row * HID + j];
    hv[e] = (1.f - zg) * ng + zg * h;
    o[e] = (short)f2bf(hv[e]);
  }
  *(f32x4*)(hnew_out + (size_t)row * HID + k0)     = (f32x4){hv[0], hv[1], hv[2], hv[3]};
  *(f32x4*)(hnew_out + (size_t)row * HID + k0 + 4) = (f32x4){hv[4], hv[5], hv[6], hv[7]};
  *(short8*)(hnbf2 + (size_t)kc * 1024 + row * 8) = o;
}

// ---------------- K3: logits GEMM — burst-sequential W tile, LDS-resident ----
// Block = 1 wave, 16 vocab rows x 128 batch, K=1024.
// Prologue: 64 gload16 fetch the block's ENTIRE W tile (contiguous 64 KB of
//   Wout) into LDS fp32, with per-instruction lane-XOR chunk swizzle on the
//   SOURCE (rule 21) so phase-2 row-strided reads are bank-spread.
// Main loop: A via 2-slot gload16 ring (8 KB chunk-major tiles), counted
//   vmcnt(8), no barriers. W read from LDS + f2bf in-loop. 80 KB LDS
//   -> 2 blocks/CU; one block's W burst overlaps the other's compute.
__global__ __launch_bounds__(64) void k3_logits(
    const ushort_t* __restrict__ Abf2, const float* __restrict__ Wout,
    const float* __restrict__ bout, float* __restrict__ out,
    float2* __restrict__ part) {
  __shared__ char Wl[16 * 4096];      // 64 KB fp32 W tile (chunk-swizzled)
  __shared__ char Al[2 * 8192];       // 16 KB A ring

  const int l = threadIdx.x;          // 0..63
  const int r = l & 15, g = l >> 4;
  const int vb = blockIdx.x * 16;

  f32x4 acc[8];
#pragma unroll
  for (int i = 0; i < 8; ++i) acc[i] = (f32x4){0.f, 0.f, 0.f, 0.f};

  // ---- W prologue: 64 back-to-back gload16, contiguous 64 KB region ----
  // Per instr: one quarter-row (1 KB); src chunk = lane ^ (row&7) (swizzle),
  // dst linear. Stored chunk p holds logical chunk p ^ (row&7).
#pragma unroll
  for (int rw = 0; rw < 16; ++rw) {
    int vr = vb + rw; if (vr > VOCAB - 1) vr = VOCAB - 1;
    const char* rowsrc = (const char*)Wout + (size_t)vr * 4096;
    const int lx = (l ^ (rw & 7)) * 16;
#pragma unroll
    for (int q = 0; q < 4; ++q)
      gload16(rowsrc + q * 1024 + lx, Wl + rw * 4096 + q * 1024);
  }
  MEMF();

  // ---- A ring stage: 8 gload16 per slot (8 KB contiguous chunk-major) ----
#define ASTAGE(T, S)                                                         \
  {                                                                          \
    _Pragma("unroll")                                                        \
    for (int i = 0; i < 8; ++i)                                              \
      gload16((const char*)Abf2 + (size_t)(T) * 8192 + i * 1024 + l * 16,    \
              Al + (S) * 8192 + i * 1024);                                   \
  }

  ASTAGE(0, 0) MEMF();
  ASTAGE(1, 1) MEMF();

  const int rx = r & 7;
  for (int t = 0; t < NKT; ++t) {
    // retire W(prologue, t=0) + A slot t; keep A slot t+1's 8 in flight
    if (t < NKT - 1) { asm volatile("s_waitcnt vmcnt(8)" ::: "memory"); }
    else             { asm volatile("s_waitcnt vmcnt(0)" ::: "memory"); }
    MEMF();
    // A fragments: kc_local = g, row = m*16 + r
    const char* ar = Al + (t & 1) * 8192 + g * 2048 + r * 16;
    short8 afr[8];
#pragma unroll
    for (int m = 0; m < 8; ++m) afr[m] = *(const short8*)(ar + m * 256);
    // W fragment: row r, logical 16B-chunks t*8+g*2, +1 at stored pos ^rx
    const char* wrow = Wl + r * 4096;
    f32x4 w0 = *(const f32x4*)(wrow + (((t * 8 + g * 2    ) ^ rx) * 16));
    f32x4 w1 = *(const f32x4*)(wrow + (((t * 8 + g * 2 + 1) ^ rx) * 16));
    MEMF();
    // stage A slot t+2 into buffer t&1 (registers above already hold slot t)
    if (t + 2 < NKT) { ASTAGE(t + 2, (t & 1)) MEMF(); }
    short8 bfr;
    bfr[0] = (short)f2bf(w0[0]); bfr[1] = (short)f2bf(w0[1]);
    bfr[2] = (short)f2bf(w0[2]); bfr[3] = (short)f2bf(w0[3]);
    bfr[4] = (short)f2bf(w1[0]); bfr[5] = (short)f2bf(w1[1]);
    bfr[6] = (short)f2bf(w1[2]); bfr[7] = (short)f2bf(w1[3]);
#pragma unroll
    for (int m = 0; m < 8; ++m)
      acc[m] = __builtin_amdgcn_mfma_f32_16x16x32_bf16(afr[m], bfr, acc[m], 0, 0, 0);
  }
#undef ASTAGE

  // ---- epilogue: bias, store logits, per-block softmax partials ----
  const int v = vb + r;
  const bool vok = (v < VOCAB);
  float bias = bout[vok ? v : VOCAB - 1];
#pragma unroll
  for (int m = 0; m < 8; ++m) {
#pragma unroll
    for (int rr = 0; rr < 4; ++rr) {
      float val = acc[m][rr] + bias;
      int b = m * 16 + g * 4 + rr;          // batch row
      if (vok) out[(size_t)b * VOCAB + v] = val;
      float sv = vok ? val : -INFINITY;
      float mx = sv;
      mx = fmaxf(mx, __shfl_xor(mx, 1));
      mx = fmaxf(mx, __shfl_xor(mx, 2));
      mx = fmaxf(mx, __shfl_xor(mx, 4));
      mx = fmaxf(mx, __shfl_xor(mx, 8));
      float ss = vok ? __expf(sv - mx) : 0.f;
      ss += __shfl_xor(ss, 1);
      ss += __shfl_xor(ss, 2);
      ss += __shfl_xor(ss, 4);
      ss += __shfl_xor(ss, 8);
      if (r == 0) part[(size_t)blockIdx.x * 128 + b] = make_float2(mx, ss);
    }
  }
}

// ---------------- K4: combine partials -> stat[b] ----------------
__global__ __launch_bounds__(256) void k4_combine(
    const float2* __restrict__ part, float* __restrict__ stat) {
  const int NP = NBK3;   // 3142 partials per batch row
  int b = blockIdx.x, t = threadIdx.x;
  float m = -INFINITY;
  for (int i = t; i < NP; i += 256) m = fmaxf(m, part[(size_t)i * 128 + b].x);
  __shared__ float red[256];
  red[t] = m; __syncthreads();
  for (int st = 128; st > 0; st >>= 1) {
    if (t < st) red[t] = fmaxf(red[t], red[t + st]);
    __syncthreads();
  }
  float M = red[0]; __syncthreads();
  float ssum = 0.f;
  for (int i = t; i < NP; i += 256) {
    float2 p = part[(size_t)i * 128 + b];
    ssum += p.y * __expf(p.x - M);
  }
  red[t] = ssum; __syncthreads();
  for (int st = 128; st > 0; st >>= 1) {
    if (t < st) red[t] += red[t + st];
    __syncthreads();
  }
  if (t == 0) stat[b] = M + logf(red[0]);
}

// ---------------- K5: out = logit - stat[b], float4 ----------------
__global__ __launch_bounds__(256) void k5_final(
    float* __restrict__ out, const float* __restrict__ stat) {
  const int total = BATCH * VOCAB;        // 6432896, divisible by 4
  int i4 = blockIdx.x * 256 + threadIdx.x;
  int base = i4 * 4;
  if (base >= total) return;
  float4 v = *(float4*)(out + base);
  int b0 = base / VOCAB, b3 = (base + 3) / VOCAB;
  if (b0 == b3) {
    float s = stat[b0];
    v.x -= s; v.y -= s; v.z -= s; v.w -= s;
  } else {
    v.x -= stat[base / VOCAB];
    v.y -= stat[(base + 1) / VOCAB];
    v.z -= stat[(base + 2) / VOCAB];
    v.w -= stat[(base + 3) / VOCAB];
  }
  *(float4*)(out + base) = v;
}

extern "C" void kernel_launch(void* const* d_in, const int* in_sizes, int n_in,
                              void* d_out, int out_size, void* d_ws, size_t ws_size,
                              hipStream_t stream) {
  const int*   ids   = (const int*)  d_in[0];
  const float* hprev = (const float*)d_in[1];
  // d_in[2] = encoder_output, unused by the reference
  const float* emb   = (const float*)d_in[3];
  const float* wih   = (const float*)d_in[4];
  const float* whh   = (const float*)d_in[5];
  const float* bih   = (const float*)d_in[6];
  const float* bhh   = (const float*)d_in[7];
  const float* Wout  = (const float*)d_in[8];
  const float* bout  = (const float*)d_in[9];
  float* out = (float*)d_out;
  char* ws = (char*)d_ws;

  // ws layout (bytes); max offset used = 12009472.
  // hnbf2 aliases dead wihbf region; part/stat alias dead whhbf region
  // (part 3142*128*8 = 3217408 B ends at 5527552 <= stat @5529600).
  ushort_t* xbf   = (ushort_t*)(ws + 0);         // 128x320 bf16
  ushort_t* hbf   = (ushort_t*)(ws + 81920);     // 128x1024 bf16
  ushort_t* wihbf = (ushort_t*)(ws + 344064);    // 3072x320 bf16 (dead after k1)
  ushort_t* whhbf = (ushort_t*)(ws + 2310144);   // 3072x1024 bf16 (dead after k1)
  float*    gi    = (float*)(ws + 8601600);      // 128x3072 f32
  float*    gh    = (float*)(ws + 10174464);     // 128x3072 f32
  ushort_t* hnbf2 = (ushort_t*)(ws + 344064);    // 128x1024 bf16 chunk-major (aliases wihbf)
  float2*   part  = (float2*)(ws + 2310144);     // 3142x128 float2 (aliases whhbf)
  float*    stat  = (float*)(ws + 5529600);      // 128 f32

  float* hnew_out = out + (size_t)BATCH * VOCAB;

  hipLaunchKernelGGL(k0_prep, dim3(6048), dim3(256), 0, stream,
                     ids, emb, hprev, wih, whh, xbf, hbf, wihbf, whhbf);
  hipLaunchKernelGGL(k1_gemm_gates, dim3(192, 2), dim3(64), 0, stream,
                     xbf, hbf, wihbf, whhbf, gi, gh);
  hipLaunchKernelGGL(k2_gates, dim3(64), dim3(256), 0, stream,
                     gi, gh, bih, bhh, hprev, hnew_out, hnbf2);
  hipLaunchKernelGGL(k3_logits, dim3(NBK3), dim3(64), 0, stream,
                     hnbf2, Wout, bout, out, part);
  hipLaunchKernelGGL(k4_combine, dim3(128), dim3(256), 0, stream, part, stat);
  hipLaunchKernelGGL(k5_final, dim3((BATCH * VOCAB / 4 + 255) / 256), dim3(256), 0, stream,
                     out, stat);
}

// Round 12
// 140.566 us; speedup vs baseline: 1.7649x; 1.7649x over previous
//
#include <hip/hip_runtime.h>

#define VOCAB 50257
#define EMBD  300
#define EMBP  320      // EMB padded to multiple of 32 for MFMA K
#define HID   1024
#define B3H   3072
#define BATCH 128
#define NBK3  1571     // ceil(50257/32) : k3 grid, 32 vocab rows/block
#define NKT   32       // K tiles of 32
#define SLOTB 12288    // bytes per ring slot: W 4KB + A 8KB

typedef __attribute__((ext_vector_type(8))) short short8;
typedef __attribute__((ext_vector_type(4))) float f32x4;
typedef unsigned short ushort_t;

__device__ __forceinline__ unsigned short f2bf(float f) {
  unsigned int u = __float_as_uint(f);
  u += 0x7fffu + ((u >> 16) & 1u);
  return (unsigned short)(u >> 16);
}

__device__ __forceinline__ void gload16(const void* g, void* l) {
  __builtin_amdgcn_global_load_lds(
      (const __attribute__((address_space(1))) void*)g,
      (__attribute__((address_space(3))) void*)l, 16, 0, 0);
}

#define MEMF() asm volatile("" ::: "memory")

// ---------------- K0: gather + bf16 casts (x, h, w_ih, w_hh) ----------------
__global__ __launch_bounds__(256) void k0_prep(
    const int* __restrict__ ids, const float* __restrict__ emb,
    const float* __restrict__ hprev, const float* __restrict__ wih,
    const float* __restrict__ whh,
    ushort_t* __restrict__ xbf, ushort_t* __restrict__ hbf,
    ushort_t* __restrict__ wihbf, ushort_t* __restrict__ whhbf) {
  const int NX  = BATCH * EMBP;        // 40960
  const int NH  = BATCH * HID;         // 131072
  const int NWI = B3H * EMBP;          // 983040
  int i = blockIdx.x * 256 + threadIdx.x;
  if (i < NX) {
    int b = i / EMBP, k = i - b * EMBP;
    float f = (k < EMBD) ? emb[(size_t)ids[b] * EMBD + k] : 0.f;
    xbf[i] = f2bf(f);
  } else if (i < NX + NH) {
    int j = i - NX;
    hbf[j] = f2bf(hprev[j]);
  } else if (i < NX + NH + NWI) {
    int j = i - NX - NH;
    int n = j / EMBP, k = j - n * EMBP;
    wihbf[j] = f2bf((k < EMBD) ? wih[(size_t)n * EMBD + k] : 0.f);
  } else {
    int j = (i - NX - NH - NWI) * 8;
    f32x4 a = *(const f32x4*)(whh + j);
    f32x4 b = *(const f32x4*)(whh + j + 4);
    short8 o;
    o[0] = (short)f2bf(a[0]); o[1] = (short)f2bf(a[1]);
    o[2] = (short)f2bf(a[2]); o[3] = (short)f2bf(a[3]);
    o[4] = (short)f2bf(b[0]); o[5] = (short)f2bf(b[1]);
    o[6] = (short)f2bf(b[2]); o[7] = (short)f2bf(b[3]);
    *(short8*)(whhbf + j) = o;
  }
}

// ---------------- K1: gates GEMMs, 1 wave per block, 16 cols, bf16 B ----------------
__global__ __launch_bounds__(64) void k1_gemm_gates(
    const ushort_t* __restrict__ xbf, const ushort_t* __restrict__ hbf,
    const ushort_t* __restrict__ wihbf, const ushort_t* __restrict__ whhbf,
    float* __restrict__ gi, float* __restrict__ gh) {
  const bool is_h = (blockIdx.y == 1);
  const ushort_t* A = is_h ? hbf : xbf;
  const ushort_t* B = is_h ? whhbf : wihbf;
  const int K = is_h ? HID : EMBP;
  const int lane = threadIdx.x;
  const int r = lane & 15, g = lane >> 4;
  const int n = blockIdx.x * 16 + r;
  const ushort_t* brow = B + (size_t)n * K;

  f32x4 acc[8];
#pragma unroll
  for (int i = 0; i < 8; i++) acc[i] = (f32x4){0.f, 0.f, 0.f, 0.f};

#pragma unroll 2
  for (int k0 = 0; k0 < K; k0 += 32) {
    short8 bfr = *(const short8*)(brow + k0 + g * 8);
#pragma unroll
    for (int mi = 0; mi < 8; mi++) {
      short8 afr = *(const short8*)(A + (size_t)(mi * 16 + r) * K + k0 + g * 8);
      acc[mi] = __builtin_amdgcn_mfma_f32_16x16x32_bf16(afr, bfr, acc[mi], 0, 0, 0);
    }
  }
  float* C = is_h ? gh : gi;
#pragma unroll
  for (int mi = 0; mi < 8; mi++)
#pragma unroll
    for (int rr = 0; rr < 4; rr++)
      C[(size_t)(mi * 16 + g * 4 + rr) * B3H + n] = acc[mi][rr];
}

// ---------------- K2: GRU gates -> h_new (f32) + chunk-major bf16 hnbf2 ----------
// hnbf2 layout: ushort idx = kchunk*1024 + row*8 + (k&7), kchunk = k>>3.
// K-tile kt (32 k) of all 128 rows = bytes [kt*8192, kt*8192+8192) CONTIGUOUS.
__global__ __launch_bounds__(256) void k2_gates(
    const float* __restrict__ gi, const float* __restrict__ gh,
    const float* __restrict__ bih, const float* __restrict__ bhh,
    const float* __restrict__ hprev,
    float* __restrict__ hnew_out, ushort_t* __restrict__ hnbf2) {
  int t = blockIdx.x * 256 + threadIdx.x;   // 0..16383
  int row = t >> 7, kc = t & 127;
  int k0 = kc * 8;
  size_t gb = (size_t)row * B3H;
  float hv[8];
  short8 o;
#pragma unroll
  for (int e = 0; e < 8; ++e) {
    int j = k0 + e;
    float ir  = gi[gb + j]           + bih[j];
    float iz  = gi[gb + HID + j]     + bih[HID + j];
    float in_ = gi[gb + 2*HID + j]   + bih[2*HID + j];
    float hr  = gh[gb + j]           + bhh[j];
    float hz  = gh[gb + HID + j]     + bhh[HID + j];
    float hn  = gh[gb + 2*HID + j]   + bhh[2*HID + j];
    float rg = 1.f / (1.f + expf(-(ir + hr)));
    float zg = 1.f / (1.f + expf(-(iz + hz)));
    float ng = tanhf(in_ + rg * hn);
    float h  = hprev[row * HID + j];
    hv[e] = (1.f - zg) * ng + zg * h;
    o[e] = (short)f2bf(hv[e]);
  }
  *(f32x4*)(hnew_out + (size_t)row * HID + k0)     = (f32x4){hv[0], hv[1], hv[2], hv[3]};
  *(f32x4*)(hnew_out + (size_t)row * HID + k0 + 4) = (f32x4){hv[4], hv[5], hv[6], hv[7]};
  *(short8*)(hnbf2 + (size_t)kc * 1024 + row * 8) = o;
}

// ---------------- K3: logits GEMM — 1-wave blocks sized for 6 waves/CU ----------
// Block = 1 wave, 32 vocab rows x 128 batch, K=1024 in 32 tiles.
// Slot (12 KB) = W (32x32 f32, 4KB, src-chunk XOR-swizzled) + A (8KB chunk-major).
// 2-slot ring (24 KB LDS -> 6 blocks/CU; grid 1571 ~ 6.1/CU, one resident round).
// Per tile: wait vmcnt(12) -> ds_read ENTIRE slot t to regs -> lgkmcnt(0)
// -> stage slot t+2 into freed buffer -> f2bf + 16 MFMA from regs. No barriers.
__global__ __launch_bounds__(64) void k3_logits(
    const ushort_t* __restrict__ Abf2, const float* __restrict__ Wout,
    const float* __restrict__ bout, float* __restrict__ out,
    float2* __restrict__ part) {
  __shared__ char At[2 * SLOTB];   // 24 KB

  const int l = threadIdx.x;          // 0..63
  const int r = l & 15, g = l >> 4;
  const int vb = blockIdx.x * 32;

  const int srow = l >> 3;            // staging: W row within 8-row group
  const int swz  = (l & 7) ^ srow;    // staging: W source 16B chunk (XOR swizzle)
  const int rx = r & 7;

  f32x4 acc[2][8];
#pragma unroll
  for (int c = 0; c < 2; ++c)
#pragma unroll
    for (int m = 0; m < 8; ++m) acc[c][m] = (f32x4){0.f, 0.f, 0.f, 0.f};

  // stage slot for K-tile T into ring buffer S: 4 W gloads + 8 A gloads
#define STAGE(T, S)                                                          \
  {                                                                          \
    char* sb = At + (size_t)(S) * SLOTB;                                     \
    _Pragma("unroll")                                                        \
    for (int i = 0; i < 4; ++i) {                                            \
      int rw = vb + i * 8 + srow; if (rw > VOCAB - 1) rw = VOCAB - 1;        \
      gload16((const char*)Wout + (size_t)rw * 4096 + (size_t)(T) * 128 + swz * 16, \
              sb + i * 1024);                                                \
    }                                                                        \
    _Pragma("unroll")                                                        \
    for (int i = 0; i < 8; ++i) {                                            \
      gload16((const char*)Abf2 + (size_t)(T) * 8192 + i * 1024 + l * 16,    \
              sb + 4096 + i * 1024);                                         \
    }                                                                        \
  }

  STAGE(0, 0) MEMF();
  STAGE(1, 1) MEMF();

  for (int t = 0; t < NKT; ++t) {
    // retire slot t's 12 loads; keep slot t+1's 12 in flight
    if (t < NKT - 1) { asm volatile("s_waitcnt vmcnt(12)" ::: "memory"); }
    else             { asm volatile("s_waitcnt vmcnt(0)"  ::: "memory"); }
    MEMF();
    const char* slot = At + (size_t)(t & 1) * SLOTB;
    // ---- read ENTIRE slot t into registers ----
    // A fragments: kc_local = g, row = m*16 + r
    short8 afr[8];
    const char* ar = slot + 4096 + g * 2048 + r * 16;
#pragma unroll
    for (int m = 0; m < 8; ++m) afr[m] = *(const short8*)(ar + m * 256);
    // W raw: col group c (rows c*16+r), logical chunks 2g, 2g+1 at pos ^rx
    f32x4 w[2][2];
#pragma unroll
    for (int c = 0; c < 2; ++c) {
      const char* wr = slot + (c * 16 + r) * 128;
      w[c][0] = *(const f32x4*)(wr + (((2 * g)     ^ rx) * 16));
      w[c][1] = *(const f32x4*)(wr + (((2 * g + 1) ^ rx) * 16));
    }
    asm volatile("s_waitcnt lgkmcnt(0)" ::: "memory");
    __builtin_amdgcn_sched_barrier(0);
    // ---- slot t buffer free: stage slot t+2 into it ----
    if (t + 2 < NKT) { STAGE(t + 2, (t & 1)) MEMF(); }
    // ---- compute from registers ----
#pragma unroll
    for (int c = 0; c < 2; ++c) {
      short8 bfr;
      bfr[0] = (short)f2bf(w[c][0][0]); bfr[1] = (short)f2bf(w[c][0][1]);
      bfr[2] = (short)f2bf(w[c][0][2]); bfr[3] = (short)f2bf(w[c][0][3]);
      bfr[4] = (short)f2bf(w[c][1][0]); bfr[5] = (short)f2bf(w[c][1][1]);
      bfr[6] = (short)f2bf(w[c][1][2]); bfr[7] = (short)f2bf(w[c][1][3]);
#pragma unroll
      for (int m = 0; m < 8; ++m)
        acc[c][m] = __builtin_amdgcn_mfma_f32_16x16x32_bf16(afr[m], bfr, acc[c][m], 0, 0, 0);
    }
  }
#undef STAGE

  // ---- epilogue: bias, store logits, per-block softmax partials ----
#pragma unroll
  for (int m = 0; m < 8; ++m) {
#pragma unroll
    for (int rr = 0; rr < 4; ++rr) {
      int b = m * 16 + g * 4 + rr;          // batch row
      float vals[2];
#pragma unroll
      for (int c = 0; c < 2; ++c) {
        int v = vb + c * 16 + r;
        bool vok = (v < VOCAB);
        float val = acc[c][m][rr] + bout[vok ? v : VOCAB - 1];
        if (vok) out[(size_t)b * VOCAB + v] = val;
        vals[c] = vok ? val : -INFINITY;
      }
      float mx = fmaxf(vals[0], vals[1]);
      mx = fmaxf(mx, __shfl_xor(mx, 1));
      mx = fmaxf(mx, __shfl_xor(mx, 2));
      mx = fmaxf(mx, __shfl_xor(mx, 4));
      mx = fmaxf(mx, __shfl_xor(mx, 8));
      float ss = 0.f;
#pragma unroll
      for (int c = 0; c < 2; ++c)
        if (vals[c] > -INFINITY) ss += __expf(vals[c] - mx);
      ss += __shfl_xor(ss, 1);
      ss += __shfl_xor(ss, 2);
      ss += __shfl_xor(ss, 4);
      ss += __shfl_xor(ss, 8);
      if (r == 0) part[(size_t)blockIdx.x * 128 + b] = make_float2(mx, ss);
    }
  }
}

// ---------------- K4: combine partials -> stat[b] ----------------
__global__ __launch_bounds__(256) void k4_combine(
    const float2* __restrict__ part, float* __restrict__ stat) {
  const int NP = NBK3;   // 1571 partials per batch row
  int b = blockIdx.x, t = threadIdx.x;
  float m = -INFINITY;
  for (int i = t; i < NP; i += 256) m = fmaxf(m, part[(size_t)i * 128 + b].x);
  __shared__ float red[256];
  red[t] = m; __syncthreads();
  for (int st = 128; st > 0; st >>= 1) {
    if (t < st) red[t] = fmaxf(red[t], red[t + st]);
    __syncthreads();
  }
  float M = red[0]; __syncthreads();
  float ssum = 0.f;
  for (int i = t; i < NP; i += 256) {
    float2 p = part[(size_t)i * 128 + b];
    ssum += p.y * __expf(p.x - M);
  }
  red[t] = ssum; __syncthreads();
  for (int st = 128; st > 0; st >>= 1) {
    if (t < st) red[t] += red[t + st];
    __syncthreads();
  }
  if (t == 0) stat[b] = M + logf(red[0]);
}

// ---------------- K5: out = logit - stat[b], float4 ----------------
__global__ __launch_bounds__(256) void k5_final(
    float* __restrict__ out, const float* __restrict__ stat) {
  const int total = BATCH * VOCAB;        // 6432896, divisible by 4
  int i4 = blockIdx.x * 256 + threadIdx.x;
  int base = i4 * 4;
  if (base >= total) return;
  float4 v = *(float4*)(out + base);
  int b0 = base / VOCAB, b3 = (base + 3) / VOCAB;
  if (b0 == b3) {
    float s = stat[b0];
    v.x -= s; v.y -= s; v.z -= s; v.w -= s;
  } else {
    v.x -= stat[base / VOCAB];
    v.y -= stat[(base + 1) / VOCAB];
    v.z -= stat[(base + 2) / VOCAB];
    v.w -= stat[(base + 3) / VOCAB];
  }
  *(float4*)(out + base) = v;
}

extern "C" void kernel_launch(void* const* d_in, const int* in_sizes, int n_in,
                              void* d_out, int out_size, void* d_ws, size_t ws_size,
                              hipStream_t stream) {
  const int*   ids   = (const int*)  d_in[0];
  const float* hprev = (const float*)d_in[1];
  // d_in[2] = encoder_output, unused by the reference
  const float* emb   = (const float*)d_in[3];
  const float* wih   = (const float*)d_in[4];
  const float* whh   = (const float*)d_in[5];
  const float* bih   = (const float*)d_in[6];
  const float* bhh   = (const float*)d_in[7];
  const float* Wout  = (const float*)d_in[8];
  const float* bout  = (const float*)d_in[9];
  float* out = (float*)d_out;
  char* ws = (char*)d_ws;

  // ws layout (bytes); max offset used = 12009472.
  // hnbf2 aliases dead wihbf region; part/stat alias dead whhbf region
  // (part 1571*128*8 = 1608704 B ends at 3918848 <= stat @5529600).
  ushort_t* xbf   = (ushort_t*)(ws + 0);         // 128x320 bf16
  ushort_t* hbf   = (ushort_t*)(ws + 81920);     // 128x1024 bf16
  ushort_t* wihbf = (ushort_t*)(ws + 344064);    // 3072x320 bf16 (dead after k1)
  ushort_t* whhbf = (ushort_t*)(ws + 2310144);   // 3072x1024 bf16 (dead after k1)
  float*    gi    = (float*)(ws + 8601600);      // 128x3072 f32
  float*    gh    = (float*)(ws + 10174464);     // 128x3072 f32
  ushort_t* hnbf2 = (ushort_t*)(ws + 344064);    // 128x1024 bf16 chunk-major (aliases wihbf)
  float2*   part  = (float2*)(ws + 2310144);     // 1571x128 float2 (aliases whhbf)
  float*    stat  = (float*)(ws + 5529600);      // 128 f32

  float* hnew_out = out + (size_t)BATCH * VOCAB;

  hipLaunchKernelGGL(k0_prep, dim3(6048), dim3(256), 0, stream,
                     ids, emb, hprev, wih, whh, xbf, hbf, wihbf, whhbf);
  hipLaunchKernelGGL(k1_gemm_gates, dim3(192, 2), dim3(64), 0, stream,
                     xbf, hbf, wihbf, whhbf, gi, gh);
  hipLaunchKernelGGL(k2_gates, dim3(64), dim3(256), 0, stream,
                     gi, gh, bih, bhh, hprev, hnew_out, hnbf2);
  hipLaunchKernelGGL(k3_logits, dim3(NBK3), dim3(64), 0, stream,
                     hnbf2, Wout, bout, out, part);
  hipLaunchKernelGGL(k4_combine, dim3(128), dim3(256), 0, stream, part, stat);
  hipLaunchKernelGGL(k5_final, dim3((BATCH * VOCAB / 4 + 255) / 256), dim3(256), 0, stream,
                     out, stat);
}